// Round 3
// baseline (942.646 us; speedup 1.0000x reference)
//
#include <hip/hip_runtime.h>

#define E_TOTAL 600000
#define NN 50000

typedef _Float16 half8 __attribute__((ext_vector_type(8)));
typedef float float4v __attribute__((ext_vector_type(4)));

__device__ __forceinline__ float gelu_tanh(float x) {
    // jax.nn.gelu default (approximate=True): 0.5x(1+tanh(0.7978845608(x+0.044715x^3)))
    float u = 0.7978845608028654f * (x + 0.044715f * x * x * x);
    float ex = __expf(2.0f * u);            // inf/0 saturate tanh to +/-1 cleanly
    float t = 1.0f - 2.0f / (ex + 1.0f);
    return 0.5f * x * (1.0f + t);
}

// Activation LDS layout with bank swizzle.
// Logical: act[row][k], chunk c = k>>3, q = k&7, idx = (c*128+row)*8+q (f16 units).
// XOR-swizzle injects row[4:3] and c[0] into bank bits [5:3] so the 64-lane
// scalar f16 stores of the layer epilogue cover all 32 banks (was 8 banks /
// 8-way conflict). Bijective per (c,row); bits >=3 only, so b128 reads stay
// 16B-aligned. Same function used on write and read.
__device__ __forceinline__ int act_idx(int c, int row, int q) {
    int idx = ((c * 128 + row) << 3) + q;
    idx ^= ((row >> 3) & 3) << 4;
    idx ^= (c & 1) << 3;
    return idx;
}

// Pack W[K][128] f32 (row-major) into MFMA B-fragment order, f16:
// P[(c*128 + col)*8 + i] = W[(8c+i)*128 + col],  c = k>>3, i = k&7
// so lane l (step s, tile t) reads 16B at ((4s+lhi)*128 + 16t+llo)*8.
// All five weight matrices packed by one kernel, range-routed.
__global__ __launch_bounds__(256) void pack_all(
    const float* __restrict__ mW1, const float* __restrict__ mW2, const float* __restrict__ mW3,
    const float* __restrict__ uW1, const float* __restrict__ uW2,
    _Float16* __restrict__ dst)
{
    int t = blockIdx.x * 256 + threadIdx.x;
    // segments (f16 elements): mW1 40960 | mW2 16384 | mW3 16384 | uW1 32768 | uW2 16384
    const float* src;
    int loc;
    if (t < 40960)        { src = mW1; loc = t; }
    else if (t < 57344)   { src = mW2; loc = t - 40960; }
    else if (t < 73728)   { src = mW3; loc = t - 57344; }
    else if (t < 106496)  { src = uW1; loc = t - 73728; }
    else if (t < 122880)  { src = uW2; loc = t - 106496; }
    else return;
    int i   = loc & 7;
    int col = (loc >> 3) & 127;
    int c   = loc >> 10;
    dst[t] = (_Float16)src[(8 * c + i) * 128 + col];
}

__device__ __forceinline__ half8 cvt8(float4v x0, float4v x1) {
    half8 a;
    a[0] = (_Float16)x0[0]; a[1] = (_Float16)x0[1]; a[2] = (_Float16)x0[2]; a[3] = (_Float16)x0[3];
    a[4] = (_Float16)x1[0]; a[5] = (_Float16)x1[1]; a[6] = (_Float16)x1[2]; a[7] = (_Float16)x1[3];
    return a;
}

// ---------------- Message MLP + scatter ----------------
// 256 threads = 4 waves; 128 edges per block; wave w owns edge-rows [32w, 32w+32).
// Layers chain through wave-private region of s_act (A-fragment layout), so no
// __syncthreads() is needed after the initial index staging (cross-lane LDS
// deps stay within one wave; compiler inserts lgkmcnt waits via aliasing).
__global__ __launch_bounds__(256) void msg_kernel(
    const float* __restrict__ h, const int* __restrict__ ei, const float* __restrict__ eattr,
    const _Float16* __restrict__ pw1, const _Float16* __restrict__ pw2, const _Float16* __restrict__ pw3,
    const float* __restrict__ mb1, const float* __restrict__ mb2, const float* __restrict__ mb3,
    float* __restrict__ agg, float* __restrict__ cnt)
{
    __shared__ int s_src[128];
    __shared__ int s_dst[128];
    __shared__ int s_mode;
    __shared__ __align__(16) _Float16 s_act[16 * 128 * 8];

    const int tid = threadIdx.x;
    const int e0  = blockIdx.x * 128;

    // edge_index dtype auto-detect: if the buffer is raw int64, every odd
    // int32 word (high word of a value < 2^31) is 0. With int32 data these
    // are random node ids; P(32 sampled values all zero) ~ (2e-5)^32 ~ 0.
    if (tid == 0) {
        int allz = 1;
        #pragma unroll
        for (int j = 1; j < 64; j += 2) allz &= (ei[j] == 0);
        s_mode = allz;
    }
    __syncthreads();

    if (tid < 128) {
        int e  = e0 + tid;
        int ec = e < E_TOTAL ? e : E_TOTAL - 1;
        int srcn, dstn;
        if (s_mode) {
            const long long* e64 = (const long long*)ei;
            srcn = (int)e64[ec];
            dstn = (int)e64[E_TOTAL + ec];
        } else {
            srcn = ei[ec];
            dstn = ei[E_TOTAL + ec];
        }
        s_src[tid] = srcn;
        s_dst[tid] = dstn;
        if (e < E_TOTAL) unsafeAtomicAdd(&cnt[dstn], 1.0f);
    }
    __syncthreads();

    const int w = tid >> 6, l = tid & 63, lhi = l >> 4, llo = l & 15;
    const int r0 = 32 * w;
    const float4v fzero = {0.0f, 0.0f, 0.0f, 0.0f};

    // Per-lane A-row sources (rows r0+llo and r0+16+llo)
    size_t srcOff[2], dstOff[2], eOff[2];
    #pragma unroll
    for (int ms = 0; ms < 2; ++ms) {
        const int row = r0 + 16 * ms + llo;
        srcOff[ms] = (size_t)s_src[row] * 128;
        dstOff[ms] = (size_t)s_dst[row] * 128;
        int e = e0 + row; if (e >= E_TOTAL) e = E_TOTAL - 1;
        eOff[ms] = (size_t)e * 64;
    }

    // ---- GEMM1: X[128][320] @ W1[320][128] ----
    float4v acc[2][8];
    #pragma unroll
    for (int ms = 0; ms < 2; ++ms)
        #pragma unroll
        for (int t = 0; t < 8; ++t) acc[ms][t] = fzero;

    #pragma unroll
    for (int s = 0; s < 10; ++s) {
        const int kbase = 32 * s + 8 * lhi;
        half8 af[2];
        #pragma unroll
        for (int ms = 0; ms < 2; ++ms) {
            const float* p;
            if (kbase < 128)      p = h + srcOff[ms] + kbase;
            else if (kbase < 256) p = h + dstOff[ms] + (kbase - 128);
            else                  p = eattr + eOff[ms] + (kbase - 256);
            float4v x0 = *(const float4v*)p;
            float4v x1 = *(const float4v*)(p + 4);
            af[ms] = cvt8(x0, x1);
        }
        const int bbase = ((4 * s + lhi) * 128 + llo) << 3;
        #pragma unroll
        for (int t = 0; t < 8; ++t) {
            const half8 b = *(const half8*)(pw1 + bbase + (t << 7));
            acc[0][t] = __builtin_amdgcn_mfma_f32_16x16x32_f16(af[0], b, acc[0][t], 0, 0, 0);
            acc[1][t] = __builtin_amdgcn_mfma_f32_16x16x32_f16(af[1], b, acc[1][t], 0, 0, 0);
        }
    }

    // bias + gelu -> s_act
    #pragma unroll
    for (int t = 0; t < 8; ++t) {
        const int col = 16 * t + llo;
        const float b1 = mb1[col];
        #pragma unroll
        for (int ms = 0; ms < 2; ++ms)
            #pragma unroll
            for (int i = 0; i < 4; ++i) {
                const int row = r0 + 16 * ms + 4 * lhi + i;
                float v = gelu_tanh(acc[ms][t][i] + b1);
                s_act[act_idx(col >> 3, row, col & 7)] = (_Float16)v;
            }
    }

    // ---- GEMM2: A1[128][128] @ W2 ----
    float4v acc2[2][8];
    #pragma unroll
    for (int ms = 0; ms < 2; ++ms)
        #pragma unroll
        for (int t = 0; t < 8; ++t) acc2[ms][t] = fzero;

    #pragma unroll
    for (int s = 0; s < 4; ++s) {
        half8 af[2];
        #pragma unroll
        for (int ms = 0; ms < 2; ++ms) {
            const int row = r0 + 16 * ms + llo;
            af[ms] = *(const half8*)&s_act[act_idx(4 * s + lhi, row, 0)];
        }
        const int bbase = ((4 * s + lhi) * 128 + llo) << 3;
        #pragma unroll
        for (int t = 0; t < 8; ++t) {
            const half8 b = *(const half8*)(pw2 + bbase + (t << 7));
            acc2[0][t] = __builtin_amdgcn_mfma_f32_16x16x32_f16(af[0], b, acc2[0][t], 0, 0, 0);
            acc2[1][t] = __builtin_amdgcn_mfma_f32_16x16x32_f16(af[1], b, acc2[1][t], 0, 0, 0);
        }
    }

    #pragma unroll
    for (int t = 0; t < 8; ++t) {
        const int col = 16 * t + llo;
        const float b2 = mb2[col];
        #pragma unroll
        for (int ms = 0; ms < 2; ++ms)
            #pragma unroll
            for (int i = 0; i < 4; ++i) {
                const int row = r0 + 16 * ms + 4 * lhi + i;
                float v = gelu_tanh(acc2[ms][t][i] + b2);
                s_act[act_idx(col >> 3, row, col & 7)] = (_Float16)v;
            }
    }

    // ---- GEMM3: A2[128][128] @ W3 ----
    float4v acc3[2][8];
    #pragma unroll
    for (int ms = 0; ms < 2; ++ms)
        #pragma unroll
        for (int t = 0; t < 8; ++t) acc3[ms][t] = fzero;

    #pragma unroll
    for (int s = 0; s < 4; ++s) {
        half8 af[2];
        #pragma unroll
        for (int ms = 0; ms < 2; ++ms) {
            const int row = r0 + 16 * ms + llo;
            af[ms] = *(const half8*)&s_act[act_idx(4 * s + lhi, row, 0)];
        }
        const int bbase = ((4 * s + lhi) * 128 + llo) << 3;
        #pragma unroll
        for (int t = 0; t < 8; ++t) {
            const half8 b = *(const half8*)(pw3 + bbase + (t << 7));
            acc3[0][t] = __builtin_amdgcn_mfma_f32_16x16x32_f16(af[0], b, acc3[0][t], 0, 0, 0);
            acc3[1][t] = __builtin_amdgcn_mfma_f32_16x16x32_f16(af[1], b, acc3[1][t], 0, 0, 0);
        }
    }

    // msgs = acc3 + mb3 ; scatter-add into agg[dst]
    float mb3v[8];
    #pragma unroll
    for (int t = 0; t < 8; ++t) mb3v[t] = mb3[16 * t + llo];

    #pragma unroll
    for (int ms = 0; ms < 2; ++ms)
        #pragma unroll
        for (int i = 0; i < 4; ++i) {
            const int row = r0 + 16 * ms + 4 * lhi + i;
            if (e0 + row < E_TOTAL) {
                const size_t dbase = (size_t)s_dst[row] * 128;
                #pragma unroll
                for (int t = 0; t < 8; ++t) {
                    const int col = 16 * t + llo;
                    unsafeAtomicAdd(&agg[dbase + col], acc3[ms][t][i] + mb3v[t]);
                }
            }
        }
}

// ---------------- Update MLP + residual + LayerNorm ----------------
__global__ __launch_bounds__(256) void upd_kernel(
    const float* __restrict__ h,
    const _Float16* __restrict__ pu1, const _Float16* __restrict__ pu2,
    const float* __restrict__ ub1, const float* __restrict__ ub2,
    const float* __restrict__ gamma, const float* __restrict__ beta,
    const float* __restrict__ agg, const float* __restrict__ cnt,
    float* __restrict__ out)
{
    __shared__ __align__(16) _Float16 s_act[16 * 128 * 8];

    const int tid = threadIdx.x;
    const int n0  = blockIdx.x * 128;
    const int w = tid >> 6, l = tid & 63, lhi = l >> 4, llo = l & 15;
    const int r0 = 32 * w;
    const float4v fzero = {0.0f, 0.0f, 0.0f, 0.0f};

    float rcp[2];
    size_t nodeOff[2];
    #pragma unroll
    for (int ms = 0; ms < 2; ++ms) {
        int node = n0 + r0 + 16 * ms + llo;
        if (node >= NN) node = NN - 1;
        nodeOff[ms] = (size_t)node * 128;
        rcp[ms] = 1.0f / (cnt[node] + 1e-8f);
    }

    // ---- GEMM U1: [h | agg/cnt][128][256] @ uW1 ----
    float4v acc[2][8];
    #pragma unroll
    for (int ms = 0; ms < 2; ++ms)
        #pragma unroll
        for (int t = 0; t < 8; ++t) acc[ms][t] = fzero;

    #pragma unroll
    for (int s = 0; s < 8; ++s) {
        const int kbase = 32 * s + 8 * lhi;
        half8 af[2];
        #pragma unroll
        for (int ms = 0; ms < 2; ++ms) {
            const float* p;
            float sc;
            if (kbase < 128) { p = h + nodeOff[ms] + kbase; sc = 1.0f; }
            else             { p = agg + nodeOff[ms] + (kbase - 128); sc = rcp[ms]; }
            float4v x0 = *(const float4v*)p;
            float4v x1 = *(const float4v*)(p + 4);
            x0 *= sc; x1 *= sc;
            af[ms] = cvt8(x0, x1);
        }
        const int bbase = ((4 * s + lhi) * 128 + llo) << 3;
        #pragma unroll
        for (int t = 0; t < 8; ++t) {
            const half8 b = *(const half8*)(pu1 + bbase + (t << 7));
            acc[0][t] = __builtin_amdgcn_mfma_f32_16x16x32_f16(af[0], b, acc[0][t], 0, 0, 0);
            acc[1][t] = __builtin_amdgcn_mfma_f32_16x16x32_f16(af[1], b, acc[1][t], 0, 0, 0);
        }
    }

    #pragma unroll
    for (int t = 0; t < 8; ++t) {
        const int col = 16 * t + llo;
        const float b1 = ub1[col];
        #pragma unroll
        for (int ms = 0; ms < 2; ++ms)
            #pragma unroll
            for (int i = 0; i < 4; ++i) {
                const int row = r0 + 16 * ms + 4 * lhi + i;
                float v = gelu_tanh(acc[ms][t][i] + b1);
                s_act[act_idx(col >> 3, row, col & 7)] = (_Float16)v;
            }
    }

    // ---- GEMM U2 ----
    float4v acc2[2][8];
    #pragma unroll
    for (int ms = 0; ms < 2; ++ms)
        #pragma unroll
        for (int t = 0; t < 8; ++t) acc2[ms][t] = fzero;

    #pragma unroll
    for (int s = 0; s < 4; ++s) {
        half8 af[2];
        #pragma unroll
        for (int ms = 0; ms < 2; ++ms) {
            const int row = r0 + 16 * ms + llo;
            af[ms] = *(const half8*)&s_act[act_idx(4 * s + lhi, row, 0)];
        }
        const int bbase = ((4 * s + lhi) * 128 + llo) << 3;
        #pragma unroll
        for (int t = 0; t < 8; ++t) {
            const half8 b = *(const half8*)(pu2 + bbase + (t << 7));
            acc2[0][t] = __builtin_amdgcn_mfma_f32_16x16x32_f16(af[0], b, acc2[0][t], 0, 0, 0);
            acc2[1][t] = __builtin_amdgcn_mfma_f32_16x16x32_f16(af[1], b, acc2[1][t], 0, 0, 0);
        }
    }

    // epilogue: +ub2 + residual h, LayerNorm per row, store
    float ub2v[8], gv[8], bv[8];
    #pragma unroll
    for (int t = 0; t < 8; ++t) {
        const int col = 16 * t + llo;
        ub2v[t] = ub2[col]; gv[t] = gamma[col]; bv[t] = beta[col];
    }

    #pragma unroll
    for (int ms = 0; ms < 2; ++ms)
        #pragma unroll
        for (int i = 0; i < 4; ++i) {
            const int noderow = n0 + r0 + 16 * ms + 4 * lhi + i;
            const int nodec = noderow < NN ? noderow : NN - 1;
            float y[8];
            float sum = 0.0f;
            #pragma unroll
            for (int t = 0; t < 8; ++t) {
                const int col = 16 * t + llo;
                float v = acc2[ms][t][i] + ub2v[t] + h[(size_t)nodec * 128 + col];
                y[t] = v; sum += v;
            }
            sum += __shfl_xor(sum, 1, 16);
            sum += __shfl_xor(sum, 2, 16);
            sum += __shfl_xor(sum, 4, 16);
            sum += __shfl_xor(sum, 8, 16);
            const float mu = sum * (1.0f / 128.0f);
            float sq = 0.0f;
            #pragma unroll
            for (int t = 0; t < 8; ++t) { float d = y[t] - mu; sq += d * d; }
            sq += __shfl_xor(sq, 1, 16);
            sq += __shfl_xor(sq, 2, 16);
            sq += __shfl_xor(sq, 4, 16);
            sq += __shfl_xor(sq, 8, 16);
            const float rs = rsqrtf(sq * (1.0f / 128.0f) + 1e-5f);
            if (noderow < NN) {
                #pragma unroll
                for (int t = 0; t < 8; ++t) {
                    const int col = 16 * t + llo;
                    out[(size_t)noderow * 128 + col] = (y[t] - mu) * rs * gv[t] + bv[t];
                }
            }
        }
}

extern "C" void kernel_launch(void* const* d_in, const int* in_sizes, int n_in,
                              void* d_out, int out_size, void* d_ws, size_t ws_size,
                              hipStream_t stream) {
    const float* h     = (const float*)d_in[0];
    const int*   ei    = (const int*)d_in[1];
    const float* eattr = (const float*)d_in[2];
    const float* mW1   = (const float*)d_in[3];
    const float* mb1   = (const float*)d_in[4];
    const float* mW2   = (const float*)d_in[5];
    const float* mb2   = (const float*)d_in[6];
    const float* mW3   = (const float*)d_in[7];
    const float* mb3   = (const float*)d_in[8];
    const float* uW1   = (const float*)d_in[9];
    const float* ub1   = (const float*)d_in[10];
    const float* uW2   = (const float*)d_in[11];
    const float* ub2   = (const float*)d_in[12];
    const float* gamma = (const float*)d_in[13];
    const float* beta  = (const float*)d_in[14];
    float* out = (float*)d_out;

    char* ws = (char*)d_ws;
    float* agg = (float*)ws;                       // 50000*128 f32 = 25.6 MB
    float* cnt = (float*)(ws + 25600000);          // 50000 f32
    _Float16* pw  = (_Float16*)(ws + 25800000);    // packed f16 weights (122880 f16)
    _Float16* pw1 = pw;                            // 320*128
    _Float16* pw2 = pw + 40960;                    // 128*128
    _Float16* pw3 = pw + 57344;                    // 128*128
    _Float16* pu1 = pw + 73728;                    // 256*128
    _Float16* pu2 = pw + 106496;                   // 128*128

    hipMemsetAsync(ws, 0, 25800000, stream);       // zero agg + cnt

    pack_all<<<480, 256, 0, stream>>>(mW1, mW2, mW3, uW1, uW2, pw);

    msg_kernel<<<(E_TOTAL + 127) / 128, 256, 0, stream>>>(
        h, ei, eattr, pw1, pw2, pw3, mb1, mb2, mb3, agg, cnt);

    upd_kernel<<<(NN + 127) / 128, 256, 0, stream>>>(
        h, pu1, pu2, ub1, ub2, gamma, beta, agg, cnt, out);
}